// Round 2
// baseline (226.254 us; speedup 1.0000x reference)
//
#include <hip/hip_runtime.h>

#define D 1024      // in_features
#define E 64        // num experts
#define TPB 256     // threads per block (4 waves)
#define TOKS 64     // tokens per block (16 per wave)
#define KSTEPS 32   // 1024 / 32 k-steps of the 16x16x32 MFMA

typedef __attribute__((ext_vector_type(8))) short bf16x8;
typedef __attribute__((ext_vector_type(8))) unsigned short u16x8;
typedef __attribute__((ext_vector_type(4))) float f32x4;
typedef __attribute__((ext_vector_type(4))) unsigned int u32x4;

__device__ __forceinline__ unsigned short bf16_rne(float f) {
    unsigned u = __builtin_bit_cast(unsigned, f);
    u += 0x7fffu + ((u >> 16) & 1u);
    return (unsigned short)(u >> 16);
}
__device__ __forceinline__ float bf16_to_f(unsigned short h) {
    unsigned u = ((unsigned)h) << 16;
    return __builtin_bit_cast(float, u);
}

__device__ __forceinline__ unsigned cvt_pk_bf16(float a, float b) {
    // dst[15:0] = bf16_rne(a), dst[31:16] = bf16_rne(b)  (hardware RNE,
    // bit-identical to bf16_rne() for normal values)
    unsigned r;
    asm("v_cvt_pk_bf16_f32 %0, %1, %2" : "=v"(r) : "v"(a), "v"(b));
    return r;
}

// Split 8 fp32 into bf16 hi (RNE) + bf16 lo (RNE of exact residual).
// Bitwise-identical values to the proven split_hi_lo() scheme, but
// 6 VALU per 2 elements (cvt_pk + shl + and + 2 sub + cvt_pk).
__device__ __forceinline__ void split8_rne(f32x4 a, f32x4 b, bf16x8& hv, bf16x8& lv) {
    float e[8];
#pragma unroll
    for (int j = 0; j < 4; ++j) { e[j] = a[j]; e[4 + j] = b[j]; }
    u32x4 hw, lw;
#pragma unroll
    for (int i = 0; i < 4; ++i) {
        float e0 = e[2 * i], e1 = e[2 * i + 1];
        unsigned hp = cvt_pk_bf16(e0, e1);
        float f0 = __builtin_bit_cast(float, hp << 16);          // value of bf16(e0)
        float f1 = __builtin_bit_cast(float, hp & 0xffff0000u);  // value of bf16(e1)
        lw[i] = cvt_pk_bf16(e0 - f0, e1 - f1);                   // residuals exact in fp32
        hw[i] = hp;
    }
    hv = __builtin_bit_cast(bf16x8, hw);
    lv = __builtin_bit_cast(bf16x8, lw);
}

// ---------------------------------------------------------------------------
// One-time prep: split W (64x1024 fp32) into RNE hi/lo bf16 (same numerics as
// the verified kernel's split_hi_lo), laid out in exact MFMA B-fragment lane
// order: record f = (ks*4 + nt)*2 + hl, each record 64 lanes x 8 bf16 (16B).
// Lane (n=lane&15, q=lane>>4) holds W[nt*16+n][ks*32 + q*8 + 0..7].
// Total 256 KB -> d_ws.
// ---------------------------------------------------------------------------
__global__ __launch_bounds__(TPB) void router_prep(
        const float* __restrict__ W, unsigned short* __restrict__ Ws) {
    int t = blockIdx.x * TPB + threadIdx.x;  // 0..8191
    int lane = t & 63;
    int nt = (t >> 6) & 3;
    int ks = t >> 8;
    int n = lane & 15, q = lane >> 4;
    const float* src = W + (size_t)(nt * 16 + n) * D + ks * 32 + q * 8;
    u16x8 hv, lv;
#pragma unroll
    for (int j = 0; j < 8; ++j) {
        float v = src[j];
        unsigned short h = bf16_rne(v);
        hv[j] = h;
        lv[j] = bf16_rne(v - bf16_to_f(h));
    }
    size_t base = ((size_t)(ks * 8 + nt * 2) * 64 + lane) * 8;
    *(u16x8*)(Ws + base)          = hv;      // hl = 0
    *(u16x8*)(Ws + base + 64 * 8) = lv;      // hl = 1 (next record)
}

// ---------------------------------------------------------------------------
// Main: barrier-free per-wave streaming GEMM.  One wave = 16 tokens.
// A (x rows, HBM) prefetched 3 k-steps deep; B (pre-split W frags, L2)
// prefetched 1 k-step deep.  No LDS in the K-loop; single barrier for the
// epilogue softmax/top-2.  Numerics bitwise-match the verified kernel:
// RNE hi/lo splits, acc init 0, bias added in epilogue, same MFMA order.
// ---------------------------------------------------------------------------
__global__ __launch_bounds__(TPB, 2) void router_main(
        const float* __restrict__ x, const unsigned short* __restrict__ Ws,
        const float* __restrict__ bias, float* __restrict__ out, int T) {
    __shared__ __align__(16) float ls[TOKS][E + 1];

    const int tid  = threadIdx.x;
    const int lane = tid & 63;
    const int wid  = tid >> 6;
    const int n    = lane & 15;
    const int q    = lane >> 4;
    const int t0   = blockIdx.x * TOKS;

    const float* arow = x + (size_t)(t0 + wid * 16 + n) * D + q * 8;
    const bf16x8* bptr = (const bf16x8*)Ws + lane;   // + f*64 selects frag f

    f32x4 acc[4];
#pragma unroll
    for (int i = 0; i < 4; ++i) acc[i] = (f32x4){0.f, 0.f, 0.f, 0.f};

    // pipeline buffers (all indices compile-time after full unroll)
    f32x4 abuf[4][2];
    bf16x8 bbuf[2][8];
#pragma unroll
    for (int p = 0; p < 3; ++p) {
        abuf[p][0] = *(const f32x4*)(arow + p * 32);
        abuf[p][1] = *(const f32x4*)(arow + p * 32 + 4);
    }
#pragma unroll
    for (int f = 0; f < 8; ++f) bbuf[0][f] = bptr[f * 64];

#pragma unroll
    for (int ks = 0; ks < KSTEPS; ++ks) {
        if (ks + 3 < KSTEPS) {
            abuf[(ks + 3) & 3][0] = *(const f32x4*)(arow + (ks + 3) * 32);
            abuf[(ks + 3) & 3][1] = *(const f32x4*)(arow + (ks + 3) * 32 + 4);
        }
        if (ks + 1 < KSTEPS) {
#pragma unroll
            for (int f = 0; f < 8; ++f)
                bbuf[(ks + 1) & 1][f] = bptr[((ks + 1) * 8 + f) * 64];
        }
        bf16x8 ah, al;
        split8_rne(abuf[ks & 3][0], abuf[ks & 3][1], ah, al);
#pragma unroll
        for (int nt = 0; nt < 4; ++nt) {
            const bf16x8 bh = bbuf[ks & 1][nt * 2];
            const bf16x8 bl = bbuf[ks & 1][nt * 2 + 1];
            acc[nt] = __builtin_amdgcn_mfma_f32_16x16x32_bf16(ah, bh, acc[nt], 0, 0, 0);
            acc[nt] = __builtin_amdgcn_mfma_f32_16x16x32_bf16(al, bh, acc[nt], 0, 0, 0);
            acc[nt] = __builtin_amdgcn_mfma_f32_16x16x32_bf16(ah, bl, acc[nt], 0, 0, 0);
        }
    }

    // logits (+bias) to LDS: C/D layout col = lane&15 (expert), row = q*4 + r
#pragma unroll
    for (int nt = 0; nt < 4; ++nt) {
        int col = nt * 16 + n;
        float bv = bias[col];
#pragma unroll
        for (int r = 0; r < 4; ++r)
            ls[wid * 16 + q * 4 + r][col] = acc[nt][r] + bv;
    }
    __syncthreads();

    if (tid < TOKS) {
        float m1 = -3.4e38f, m2 = -3.4e38f;
        int i1 = 0, i2 = 0;
        for (int e = 0; e < E; ++e) {
            float v = ls[tid][e];
            if (v > m1) { m2 = m1; i2 = i1; m1 = v; i1 = e; }
            else if (v > m2) { m2 = v; i2 = e; }
        }
        float Z = 0.f;
        for (int e = 0; e < E; ++e) Z += __expf(ls[tid][e] - m1);
        float inv = 1.f / Z;
        int gt = t0 + tid;
        out[(size_t)gt * 2]     = inv;                  // exp(m1-m1)/Z
        out[(size_t)gt * 2 + 1] = __expf(m2 - m1) * inv;
        float* oi = out + (size_t)T * 2;
        oi[(size_t)gt * 2]     = (float)i1;             // indices as floats
        oi[(size_t)gt * 2 + 1] = (float)i2;
    }
}

extern "C" void kernel_launch(void* const* d_in, const int* in_sizes, int n_in,
                              void* d_out, int out_size, void* d_ws, size_t ws_size,
                              hipStream_t stream) {
    const float* x = (const float*)d_in[0];
    const float* W = (const float*)d_in[1];
    const float* b = (const float*)d_in[2];
    float* out = (float*)d_out;
    unsigned short* Ws = (unsigned short*)d_ws;   // needs 256 KB
    int T = in_sizes[0] / D;                      // 32768 tokens
    hipLaunchKernelGGL(router_prep, dim3(32), dim3(TPB), 0, stream, W, Ws);
    hipLaunchKernelGGL(router_main, dim3(T / TOKS), dim3(TPB), 0, stream,
                       x, Ws, b, out, T);
}

// Round 3
// 218.030 us; speedup vs baseline: 1.0377x; 1.0377x over previous
//
#include <hip/hip_runtime.h>

#define D 1024      // in_features
#define E 64        // num experts
#define TPB 256     // threads per block (4 waves)
#define TOKS 64     // tokens per block (16 per wave)
#define KSTEPS 32   // 1024 / 32 k-steps of the 16x16x32 MFMA

typedef __attribute__((ext_vector_type(8))) short bf16x8;
typedef __attribute__((ext_vector_type(8))) unsigned short u16x8;
typedef __attribute__((ext_vector_type(4))) float f32x4;
typedef __attribute__((ext_vector_type(4))) unsigned int u32x4;

__device__ __forceinline__ unsigned short bf16_rne(float f) {
    unsigned u = __builtin_bit_cast(unsigned, f);
    u += 0x7fffu + ((u >> 16) & 1u);
    return (unsigned short)(u >> 16);
}
__device__ __forceinline__ float bf16_to_f(unsigned short h) {
    unsigned u = ((unsigned)h) << 16;
    return __builtin_bit_cast(float, u);
}
__device__ __forceinline__ unsigned cvt_pk_bf16(float a, float b) {
    // dst[15:0] = bf16_rne(a), dst[31:16] = bf16_rne(b)  (hardware RNE,
    // bit-identical to bf16_rne() for normal values)
    unsigned r;
    asm("v_cvt_pk_bf16_f32 %0, %1, %2" : "=v"(r) : "v"(a), "v"(b));
    return r;
}
__device__ __forceinline__ float lo_val(unsigned p) {   // value of bf16 in p[15:0]
    return __builtin_bit_cast(float, p << 16);
}
__device__ __forceinline__ float hi_val(unsigned p) {   // value of bf16 in p[31:16]
    return __builtin_bit_cast(float, p & 0xffff0000u);
}

// Pipeline stage types: named members only — no runtime-indexed arrays
// anywhere in the hot loop (rule #20: arrays get demoted to scratch; the
// previous round's VGPR_Count=32 proves it happened).
struct Afrag { f32x4 u, v; };
struct Bfrag { bf16x8 f0, f1, f2, f3, f4, f5, f6, f7; };

// Split 8 fp32 into bf16 hi (RNE) + bf16 lo (RNE of exact residual).
// Bitwise-identical values to the verified split_hi_lo scheme. Array-free.
__device__ __forceinline__ void split8_rne(f32x4 a, f32x4 b, bf16x8& hv, bf16x8& lv) {
    unsigned h0 = cvt_pk_bf16(a[0], a[1]);
    unsigned h1 = cvt_pk_bf16(a[2], a[3]);
    unsigned h2 = cvt_pk_bf16(b[0], b[1]);
    unsigned h3 = cvt_pk_bf16(b[2], b[3]);
    unsigned l0 = cvt_pk_bf16(a[0] - lo_val(h0), a[1] - hi_val(h0));
    unsigned l1 = cvt_pk_bf16(a[2] - lo_val(h1), a[3] - hi_val(h1));
    unsigned l2 = cvt_pk_bf16(b[0] - lo_val(h2), b[1] - hi_val(h2));
    unsigned l3 = cvt_pk_bf16(b[2] - lo_val(h3), b[3] - hi_val(h3));
    hv = __builtin_bit_cast(bf16x8, (u32x4){h0, h1, h2, h3});
    lv = __builtin_bit_cast(bf16x8, (u32x4){l0, l1, l2, l3});
}

// ---------------------------------------------------------------------------
// One-time prep: split W (64x1024 fp32) into RNE hi/lo bf16, laid out in
// exact MFMA B-fragment lane order: record f = (ks*4 + nt)*2 + hl, each
// record 64 lanes x 8 bf16 (16B/lane).  Lane (n=lane&15, q=lane>>4) holds
// W[nt*16+n][ks*32 + q*8 + 0..7].  256 KB total -> d_ws.
// ---------------------------------------------------------------------------
__global__ __launch_bounds__(TPB) void router_prep(
        const float* __restrict__ W, unsigned short* __restrict__ Ws) {
    int t = blockIdx.x * TPB + threadIdx.x;  // 0..8191
    int lane = t & 63;
    int nt = (t >> 6) & 3;
    int ks = t >> 8;
    int n = lane & 15, q = lane >> 4;
    const float* src = W + (size_t)(nt * 16 + n) * D + ks * 32 + q * 8;
    u16x8 hv, lv;
#pragma unroll
    for (int j = 0; j < 8; ++j) {
        float v = src[j];
        unsigned short h = bf16_rne(v);
        hv[j] = h;
        lv[j] = bf16_rne(v - bf16_to_f(h));
    }
    size_t base = ((size_t)(ks * 8 + nt * 2) * 64 + lane) * 8;
    *(u16x8*)(Ws + base)          = hv;      // hl = 0
    *(u16x8*)(Ws + base + 64 * 8) = lv;      // hl = 1 (next record)
}

// ---------------------------------------------------------------------------
// Main: barrier-free per-wave streaming GEMM, software-pipelined with NAMED
// register stages.  A (x rows, HBM) 3 k-steps deep; B (pre-split W frags,
// L2-resident 256 KB) 2 k-steps deep.  B issued before A each step so the
// vmcnt FIFO wait for B never has to retire a younger HBM A-load.
// Numerics bitwise-match the verified kernel.
// ---------------------------------------------------------------------------
__global__ __launch_bounds__(TPB, 2) void router_main(
        const float* __restrict__ x, const unsigned short* __restrict__ Ws,
        const float* __restrict__ bias, float* __restrict__ out, int T) {
    __shared__ __align__(16) float ls[TOKS][E + 1];

    const int tid  = threadIdx.x;
    const int lane = tid & 63;
    const int wid  = tid >> 6;
    const int n    = lane & 15;
    const int q    = lane >> 4;
    const int t0   = blockIdx.x * TOKS;

    const float* arow = x + (size_t)(t0 + wid * 16 + n) * D + q * 8;
    const bf16x8* bptr = (const bf16x8*)Ws + lane;

    f32x4 c0 = {0.f, 0.f, 0.f, 0.f}, c1 = c0, c2 = c0, c3 = c0;
    bf16x8 ah, al;

#define LOADA(A_, ks_) do {                                   \
        A_.u = *(const f32x4*)(arow + (ks_) * 32);            \
        A_.v = *(const f32x4*)(arow + (ks_) * 32 + 4);        \
    } while (0)

#define LOADB(B_, ks_) do {                                   \
        const bf16x8* _p = bptr + (size_t)(ks_) * 512;        \
        B_.f0 = _p[0];   B_.f1 = _p[64];  B_.f2 = _p[128];    \
        B_.f3 = _p[192]; B_.f4 = _p[256]; B_.f5 = _p[320];    \
        B_.f6 = _p[384]; B_.f7 = _p[448];                     \
    } while (0)

#define MFMA __builtin_amdgcn_mfma_f32_16x16x32_bf16
#define COMP(B_) do {                                                       \
        c0 = MFMA(ah, B_.f0, c0, 0, 0, 0);                                  \
        c0 = MFMA(al, B_.f0, c0, 0, 0, 0);                                  \
        c0 = MFMA(ah, B_.f1, c0, 0, 0, 0);                                  \
        c1 = MFMA(ah, B_.f2, c1, 0, 0, 0);                                  \
        c1 = MFMA(al, B_.f2, c1, 0, 0, 0);                                  \
        c1 = MFMA(ah, B_.f3, c1, 0, 0, 0);                                  \
        c2 = MFMA(ah, B_.f4, c2, 0, 0, 0);                                  \
        c2 = MFMA(al, B_.f4, c2, 0, 0, 0);                                  \
        c2 = MFMA(ah, B_.f5, c2, 0, 0, 0);                                  \
        c3 = MFMA(ah, B_.f6, c3, 0, 0, 0);                                  \
        c3 = MFMA(al, B_.f6, c3, 0, 0, 0);                                  \
        c3 = MFMA(ah, B_.f7, c3, 0, 0, 0);                                  \
    } while (0)

// One steady-state step: issue B(ks+2) and A(ks+3) prefetch (B first),
// then split A(ks) and run the 12 MFMAs against B(ks).
#define STEP(ks_, Ause_, Afill_, Buse_, Bfill_) do {          \
        LOADB(Bfill_, (ks_) + 2);                             \
        LOADA(Afill_, (ks_) + 3);                             \
        split8_rne(Ause_.u, Ause_.v, ah, al);                 \
        COMP(Buse_);                                          \
    } while (0)

    Afrag A0, A1, A2, A3;
    Bfrag B0, B1, B2, B3;

    // prologue: A depth 3, B depth 2
    LOADA(A0, 0); LOADA(A1, 1); LOADA(A2, 2);
    LOADB(B0, 0); LOADB(B1, 1);

    // steady state: ks = 0..27, manually unrolled by 4 (all stage names static)
    for (int kb = 0; kb < KSTEPS - 4; kb += 4) {
        STEP(kb + 0, A0, A3, B0, B2);
        STEP(kb + 1, A1, A0, B1, B3);
        STEP(kb + 2, A2, A1, B2, B0);
        STEP(kb + 3, A3, A2, B3, B1);
    }

    // epilogue: ks = 28..31 (guarded fills written out explicitly)
    LOADB(B2, 30); LOADA(A3, 31);
    split8_rne(A0.u, A0.v, ah, al); COMP(B0);   // ks = 28
    LOADB(B3, 31);
    split8_rne(A1.u, A1.v, ah, al); COMP(B1);   // ks = 29
    split8_rne(A2.u, A2.v, ah, al); COMP(B2);   // ks = 30
    split8_rne(A3.u, A3.v, ah, al); COMP(B3);   // ks = 31

    // logits (+bias) to LDS: C/D layout col = lane&15 (expert), row = q*4 + r
    {
        const int row = wid * 16 + q * 4;
#define STORE_C(c_, nt_) do {                                 \
            int col = (nt_) * 16 + n;                         \
            float bv = bias[col];                             \
            ls[row + 0][col] = c_[0] + bv;                    \
            ls[row + 1][col] = c_[1] + bv;                    \
            ls[row + 2][col] = c_[2] + bv;                    \
            ls[row + 3][col] = c_[3] + bv;                    \
        } while (0)
        STORE_C(c0, 0); STORE_C(c1, 1); STORE_C(c2, 2); STORE_C(c3, 3);
#undef STORE_C
    }
    __syncthreads();

    if (tid < TOKS) {
        float m1 = -3.4e38f, m2 = -3.4e38f;
        int i1 = 0, i2 = 0;
        for (int e = 0; e < E; ++e) {
            float v = ls[tid][e];
            if (v > m1) { m2 = m1; i2 = i1; m1 = v; i1 = e; }
            else if (v > m2) { m2 = v; i2 = e; }
        }
        float Z = 0.f;
        for (int e = 0; e < E; ++e) Z += __expf(ls[tid][e] - m1);
        float inv = 1.f / Z;
        int gt = t0 + tid;
        out[(size_t)gt * 2]     = inv;                  // exp(m1-m1)/Z
        out[(size_t)gt * 2 + 1] = __expf(m2 - m1) * inv;
        float* oi = out + (size_t)T * 2;
        oi[(size_t)gt * 2]     = (float)i1;             // indices as floats
        oi[(size_t)gt * 2 + 1] = (float)i2;
    }
}

extern "C" void kernel_launch(void* const* d_in, const int* in_sizes, int n_in,
                              void* d_out, int out_size, void* d_ws, size_t ws_size,
                              hipStream_t stream) {
    const float* x = (const float*)d_in[0];
    const float* W = (const float*)d_in[1];
    const float* b = (const float*)d_in[2];
    float* out = (float*)d_out;
    unsigned short* Ws = (unsigned short*)d_ws;   // needs 256 KB
    int T = in_sizes[0] / D;                      // 32768 tokens
    hipLaunchKernelGGL(router_prep, dim3(32), dim3(TPB), 0, stream, W, Ws);
    hipLaunchKernelGGL(router_main, dim3(T / TOKS), dim3(TPB), 0, stream,
                       x, Ws, b, out, T);
}

// Round 4
// 212.720 us; speedup vs baseline: 1.0636x; 1.0250x over previous
//
#include <hip/hip_runtime.h>

#define D 1024      // in_features
#define E 64        // num experts
#define TPB 256     // threads per block (4 waves)
#define TOKS 64     // tokens per block (16 per wave)
#define KSTEPS 32   // 1024 / 32 k-steps of the 16x16x32 MFMA
#define PH_KS 8     // k-steps per LDS phase
#define PHASES 4

typedef __attribute__((ext_vector_type(8))) short bf16x8;
typedef __attribute__((ext_vector_type(8))) unsigned short u16x8;
typedef __attribute__((ext_vector_type(4))) float f32x4;
typedef __attribute__((ext_vector_type(4))) unsigned int u32x4;

__device__ __forceinline__ unsigned short bf16_rne(float f) {
    unsigned u = __builtin_bit_cast(unsigned, f);
    u += 0x7fffu + ((u >> 16) & 1u);
    return (unsigned short)(u >> 16);
}
__device__ __forceinline__ float bf16_to_f(unsigned short h) {
    unsigned u = ((unsigned)h) << 16;
    return __builtin_bit_cast(float, u);
}
__device__ __forceinline__ unsigned cvt_pk_bf16(float a, float b) {
    // dst[15:0] = bf16_rne(a), dst[31:16] = bf16_rne(b)  (hardware RNE,
    // bit-identical to bf16_rne() for normal values)
    unsigned r;
    asm("v_cvt_pk_bf16_f32 %0, %1, %2" : "=v"(r) : "v"(a), "v"(b));
    return r;
}
__device__ __forceinline__ float lo_val(unsigned p) {
    return __builtin_bit_cast(float, p << 16);
}
__device__ __forceinline__ float hi_val(unsigned p) {
    return __builtin_bit_cast(float, p & 0xffff0000u);
}

// Named-member pipeline stages only — no runtime-indexed register arrays
// (rule #20: those demote to scratch; round-2's VGPR_Count=32 proved it).
struct Afrag { f32x4 u, v; };
struct Bfrag { bf16x8 f0, f1, f2, f3, f4, f5, f6, f7; };

// Split 8 fp32 into bf16 hi (RNE) + bf16 lo (RNE of exact residual).
// Bitwise-identical values to the verified split_hi_lo scheme.
__device__ __forceinline__ void split8_rne(f32x4 a, f32x4 b, bf16x8& hv, bf16x8& lv) {
    unsigned h0 = cvt_pk_bf16(a[0], a[1]);
    unsigned h1 = cvt_pk_bf16(a[2], a[3]);
    unsigned h2 = cvt_pk_bf16(b[0], b[1]);
    unsigned h3 = cvt_pk_bf16(b[2], b[3]);
    unsigned l0 = cvt_pk_bf16(a[0] - lo_val(h0), a[1] - hi_val(h0));
    unsigned l1 = cvt_pk_bf16(a[2] - lo_val(h1), a[3] - hi_val(h1));
    unsigned l2 = cvt_pk_bf16(b[0] - lo_val(h2), b[1] - hi_val(h2));
    unsigned l3 = cvt_pk_bf16(b[2] - lo_val(h3), b[3] - hi_val(h3));
    hv = __builtin_bit_cast(bf16x8, (u32x4){h0, h1, h2, h3});
    lv = __builtin_bit_cast(bf16x8, (u32x4){l0, l1, l2, l3});
}

// ---------------------------------------------------------------------------
// One-time prep: split W (64x1024 fp32) into RNE hi/lo bf16, laid out in
// exact MFMA B-fragment lane order: record f = (ks*4 + nt)*2 + hl, each
// record 64 lanes x 8 bf16 (16B/lane).  Lane (n=lane&15, q=lane>>4) holds
// W[nt*16+n][ks*32 + q*8 + 0..7].  256 KB total -> d_ws.  (Unchanged, proven.)
// ---------------------------------------------------------------------------
__global__ __launch_bounds__(TPB) void router_prep(
        const float* __restrict__ W, unsigned short* __restrict__ Ws) {
    int t = blockIdx.x * TPB + threadIdx.x;  // 0..8191
    int lane = t & 63;
    int nt = (t >> 6) & 3;
    int ks = t >> 8;
    int n = lane & 15, q = lane >> 4;
    const float* src = W + (size_t)(nt * 16 + n) * D + ks * 32 + q * 8;
    u16x8 hv, lv;
#pragma unroll
    for (int j = 0; j < 8; ++j) {
        float v = src[j];
        unsigned short h = bf16_rne(v);
        hv[j] = h;
        lv[j] = bf16_rne(v - bf16_to_f(h));
    }
    size_t base = ((size_t)(ks * 8 + nt * 2) * 64 + lane) * 8;
    *(u16x8*)(Ws + base)          = hv;      // hl = 0
    *(u16x8*)(Ws + base + 64 * 8) = lv;      // hl = 1 (next record)
}

// ---------------------------------------------------------------------------
// Main: B shared block-wide via LDS (4 phases x 64 KB), A per-wave in a
// depth-2 NAMED register pipeline that carries across phase barriers.
// VGPR pressure ~130 (vs ~240 with per-wave B in regs) so the A prefetch
// schedule survives regalloc.  Global traffic: A 134 MB + B 134 MB (was
// 512 MB per-wave B).  8 barriers total (was 32 in the original design).
// Numerics bitwise-match the verified kernel.
// ---------------------------------------------------------------------------
__global__ __launch_bounds__(TPB, 2) void router_main(
        const float* __restrict__ x, const unsigned short* __restrict__ Ws,
        const float* __restrict__ bias, float* __restrict__ out, int T) {
    __shared__ __align__(16) union SM {
        unsigned short w[PH_KS * 8 * 64 * 8];   // 64 KB staged B chunk
        float ls[TOKS][E + 1];
    } sm;

    const int tid  = threadIdx.x;
    const int lane = tid & 63;
    const int wid  = tid >> 6;
    const int n    = lane & 15;
    const int q    = lane >> 4;
    const int t0   = blockIdx.x * TOKS;

    const float* arow = x + (size_t)(t0 + wid * 16 + n) * D + q * 8;

    f32x4 c0 = {0.f, 0.f, 0.f, 0.f}, c1 = c0, c2 = c0, c3 = c0;
    bf16x8 ah, al;
    Afrag A0, A1;
    Bfrag Bt;

#define LOADA(A_, ks_) do {                                   \
        A_.u = *(const f32x4*)(arow + (ks_) * 32);            \
        A_.v = *(const f32x4*)(arow + (ks_) * 32 + 4);        \
    } while (0)

#define LDSB(kk_) do {                                                      \
        const bf16x8* _qq = (const bf16x8*)sm.w + (kk_) * 512 + lane;       \
        Bt.f0 = _qq[0];   Bt.f1 = _qq[64];  Bt.f2 = _qq[128];               \
        Bt.f3 = _qq[192]; Bt.f4 = _qq[256]; Bt.f5 = _qq[320];               \
        Bt.f6 = _qq[384]; Bt.f7 = _qq[448];                                 \
    } while (0)

#define MFMA __builtin_amdgcn_mfma_f32_16x16x32_bf16
#define COMP() do {                                                         \
        c0 = MFMA(ah, Bt.f0, c0, 0, 0, 0);                                  \
        c0 = MFMA(al, Bt.f0, c0, 0, 0, 0);                                  \
        c0 = MFMA(ah, Bt.f1, c0, 0, 0, 0);                                  \
        c1 = MFMA(ah, Bt.f2, c1, 0, 0, 0);                                  \
        c1 = MFMA(al, Bt.f2, c1, 0, 0, 0);                                  \
        c1 = MFMA(ah, Bt.f3, c1, 0, 0, 0);                                  \
        c2 = MFMA(ah, Bt.f4, c2, 0, 0, 0);                                  \
        c2 = MFMA(al, Bt.f4, c2, 0, 0, 0);                                  \
        c2 = MFMA(ah, Bt.f5, c2, 0, 0, 0);                                  \
        c3 = MFMA(ah, Bt.f6, c3, 0, 0, 0);                                  \
        c3 = MFMA(al, Bt.f6, c3, 0, 0, 0);                                  \
        c3 = MFMA(ah, Bt.f7, c3, 0, 0, 0);                                  \
    } while (0)

    // A pipeline prologue (depth 2); refills at kk=6/7 of each phase carry
    // the prefetch across the phase barrier (vmcnt(0) drain completes them).
    LOADA(A0, 0);
    LOADA(A1, 1);

    const u32x4* gws = (const u32x4*)Ws + tid;
    u32x4* lws = (u32x4*)sm.w + tid;

    for (int p = 0; p < PHASES; ++p) {
        const int ksb = p * PH_KS;
        // ---- stage 64 KB chunk p: 16 x 16B per thread, two batches of 8 ----
        {
            const u32x4* g = gws + p * 4096;
            u32x4 s0 = g[0],    s1 = g[256],  s2 = g[512],  s3 = g[768];
            u32x4 s4 = g[1024], s5 = g[1280], s6 = g[1536], s7 = g[1792];
            lws[0]    = s0; lws[256]  = s1; lws[512]  = s2; lws[768]  = s3;
            lws[1024] = s4; lws[1280] = s5; lws[1536] = s6; lws[1792] = s7;
            u32x4 s8  = g[2048], s9  = g[2304], s10 = g[2560], s11 = g[2816];
            u32x4 s12 = g[3072], s13 = g[3328], s14 = g[3584], s15 = g[3840];
            lws[2048] = s8;  lws[2304] = s9;  lws[2560] = s10; lws[2816] = s11;
            lws[3072] = s12; lws[3328] = s13; lws[3584] = s14; lws[3840] = s15;
        }
        __syncthreads();

        // ---- 8 k-steps from LDS, A depth-2 register pipeline ----
#pragma unroll
        for (int kk = 0; kk < PH_KS; kk += 2) {
            {
                split8_rne(A0.u, A0.v, ah, al);
                int kpre = ksb + kk + 2; if (kpre > KSTEPS - 1) kpre = KSTEPS - 1;
                LOADA(A0, kpre);
                LDSB(kk);
                COMP();
            }
            {
                split8_rne(A1.u, A1.v, ah, al);
                int kpre = ksb + kk + 3; if (kpre > KSTEPS - 1) kpre = KSTEPS - 1;
                LOADA(A1, kpre);
                LDSB(kk + 1);
                COMP();
            }
        }
        __syncthreads();
    }

    // ---- epilogue: logits (+bias) to LDS (reuses chunk buffer), softmax+top2
    {
        const int row = wid * 16 + q * 4;
#define STORE_C(c_, nt_) do {                                 \
            int col = (nt_) * 16 + n;                         \
            float bv = bias[col];                             \
            sm.ls[row + 0][col] = c_[0] + bv;                 \
            sm.ls[row + 1][col] = c_[1] + bv;                 \
            sm.ls[row + 2][col] = c_[2] + bv;                 \
            sm.ls[row + 3][col] = c_[3] + bv;                 \
        } while (0)
        STORE_C(c0, 0); STORE_C(c1, 1); STORE_C(c2, 2); STORE_C(c3, 3);
#undef STORE_C
    }
    __syncthreads();

    if (tid < TOKS) {
        float m1 = -3.4e38f, m2 = -3.4e38f;
        int i1 = 0, i2 = 0;
        for (int e = 0; e < E; ++e) {
            float v = sm.ls[tid][e];
            if (v > m1) { m2 = m1; i2 = i1; m1 = v; i1 = e; }
            else if (v > m2) { m2 = v; i2 = e; }
        }
        float Z = 0.f;
        for (int e = 0; e < E; ++e) Z += __expf(sm.ls[tid][e] - m1);
        float inv = 1.f / Z;
        int gt = t0 + tid;
        out[(size_t)gt * 2]     = inv;                  // exp(m1-m1)/Z
        out[(size_t)gt * 2 + 1] = __expf(m2 - m1) * inv;
        float* oi = out + (size_t)T * 2;
        oi[(size_t)gt * 2]     = (float)i1;             // indices as floats
        oi[(size_t)gt * 2 + 1] = (float)i2;
    }
}

extern "C" void kernel_launch(void* const* d_in, const int* in_sizes, int n_in,
                              void* d_out, int out_size, void* d_ws, size_t ws_size,
                              hipStream_t stream) {
    const float* x = (const float*)d_in[0];
    const float* W = (const float*)d_in[1];
    const float* b = (const float*)d_in[2];
    float* out = (float*)d_out;
    unsigned short* Ws = (unsigned short*)d_ws;   // needs 256 KB
    int T = in_sizes[0] / D;                      // 32768 tokens
    hipLaunchKernelGGL(router_prep, dim3(32), dim3(TPB), 0, stream, W, Ws);
    hipLaunchKernelGGL(router_main, dim3(T / TOKS), dim3(TPB), 0, stream,
                       x, Ws, b, out, T);
}